// Round 22
// baseline (400.023 us; speedup 1.0000x reference)
//
#include <hip/hip_runtime.h>
#include <hip/hip_bf16.h>

#define NEG_SLOPE 0.2f

typedef __attribute__((ext_vector_type(8))) short bf16x8;
typedef __attribute__((ext_vector_type(4))) float f32x4;
typedef __attribute__((ext_vector_type(2))) float f32x2;

__device__ __forceinline__ unsigned short bf16bits(float f) {
    __hip_bfloat16 t = __float2bfloat16(f);
    return *reinterpret_cast<unsigned short*>(&t);
}

// MFMA node transform: 256 threads = 4 waves; block computes 64 nodes x FOUT.
template <int FIN, int FOUT>
__global__ __launch_bounds__(256) void node_linear(
    const float* __restrict__ x, const float* __restrict__ W,
    const float* __restrict__ att_s, const float* __restrict__ att_d,
    __hip_bfloat16* __restrict__ h, float* __restrict__ a_s, float* __restrict__ a_d, int n)
{
    constexpr int RS = FIN + 8;               // padded stride (bf16 units)
    __shared__ unsigned short xt[64 * RS];
    __shared__ unsigned short Wt[FOUT * RS];
    const int tid = threadIdx.x;
    const int base = blockIdx.x * 64;

    for (int i = tid; i < 64 * FIN / 2; i += 256) {
        int node = i / (FIN / 2);
        int k2 = i % (FIN / 2);
        f32x2 v = {0.f, 0.f};
        if (base + node < n) {
            const f32x2* p = (const f32x2*)(x + (size_t)(base + node) * FIN + k2 * 2);
            v = __builtin_nontemporal_load(p);   // x is streamed once
        }
        unsigned pk = (unsigned)bf16bits(v.x) | ((unsigned)bf16bits(v.y) << 16);
        *(unsigned*)(&xt[node * RS + k2 * 2]) = pk;
    }
    for (int i = tid; i < FIN * FOUT; i += 256) {
        int k = i / FOUT, f = i % FOUT;
        Wt[f * RS + k] = bf16bits(W[i]);
    }
    __syncthreads();

    const int wv = tid >> 6, lane = tid & 63;
    const int m = lane & 15, b = lane >> 4;
    const int node0 = base + wv * 16;

    float ps[4] = {0,0,0,0}, pd[4] = {0,0,0,0};
    #pragma unroll
    for (int t = 0; t < FOUT / 16; ++t) {
        f32x4 acc = {0.f, 0.f, 0.f, 0.f};
        #pragma unroll
        for (int ks = 0; ks < FIN / 32; ++ks) {
            bf16x8 a  = *(const bf16x8*)(&xt[(wv * 16 + m) * RS + ks * 32 + b * 8]);
            bf16x8 bb = *(const bf16x8*)(&Wt[(t * 16 + m) * RS + ks * 32 + b * 8]);
            acc = __builtin_amdgcn_mfma_f32_16x16x32_bf16(a, bb, acc, 0, 0, 0);
        }
        const float as_c = att_s[t * 16 + m];
        const float ad_c = att_d[t * 16 + m];
        #pragma unroll
        for (int r = 0; r < 4; ++r) {
            float v = acc[r];
            int node = node0 + b * 4 + r;
            if (node < n) h[(size_t)node * FOUT + t * 16 + m] = __float2bfloat16(v);
            ps[r] = fmaf(v, as_c, ps[r]);
            pd[r] = fmaf(v, ad_c, pd[r]);
        }
    }
    #pragma unroll
    for (int r = 0; r < 4; ++r) {
        float s = ps[r], d = pd[r];
        #pragma unroll
        for (int o = 8; o > 0; o >>= 1) { s += __shfl_xor(s, o); d += __shfl_xor(d, o); }
        int node = node0 + b * 4 + r;
        if (m == 0 && node < n) { a_s[node] = s; a_d[node] = d; }
    }
}

// ---- CSR build: SB hist -> tiny scan -> per-chunk SB bin -> per-SB sort ----

__global__ __launch_bounds__(256) void sb_hist(
    const int* __restrict__ edst, int E, int n, int* __restrict__ sbhist)
{
    __shared__ int lh[256];
    const int tid = threadIdx.x;
    lh[tid] = 0;
    __syncthreads();
    const int Etot = E + n;
    const int stride = gridDim.x * 256;
    for (int i = blockIdx.x * 256 + tid; i < Etot; i += stride) {
        int d = (i < E) ? __builtin_nontemporal_load(edst + i) : i - E;
        atomicAdd(&lh[d >> 9], 1);
    }
    __syncthreads();
    if (lh[tid] > 0) atomicAdd(&sbhist[tid], lh[tid]);
}

__global__ __launch_bounds__(256) void sb_scan(
    const int* __restrict__ sbhist, int nsb, int Etot,
    int* __restrict__ sbbase, int* __restrict__ sbcur)
{
    __shared__ int buf[256];
    const int tid = threadIdx.x;
    int v = (tid < nsb) ? sbhist[tid] : 0;
    buf[tid] = v;
    __syncthreads();
    for (int off = 1; off < 256; off <<= 1) {
        int t = (tid >= off) ? buf[tid - off] : 0;
        __syncthreads();
        buf[tid] += t;
        __syncthreads();
    }
    if (tid < nsb) {
        int ex = buf[tid] - v;
        sbbase[tid] = ex;
        sbcur[tid] = ex;
    }
    if (tid == 0) sbbase[nsb] = Etot;
}

#define CB_CHUNK 4096
#define CB_NSB_MAX 256
__global__ __launch_bounds__(256) void chunk_bin(
    const int* __restrict__ esrc, const int* __restrict__ edst, int E, int n,
    int nsb, int* __restrict__ sbcur, int* __restrict__ packed1)
{
    __shared__ int pk[CB_CHUNK];
    __shared__ unsigned short sbv[CB_CHUNK];
    __shared__ int hist[CB_NSB_MAX];
    __shared__ int gbase[CB_NSB_MAX];
    const int tid = threadIdx.x;
    const int i0 = blockIdx.x * CB_CHUNK;
    const int Etot = E + n;

    hist[tid] = 0;
    __syncthreads();

    for (int j = tid; j < CB_CHUNK; j += 256) {
        int i = i0 + j;
        if (i < Etot) {
            int s, d;
            if (i < E) {
                s = __builtin_nontemporal_load(esrc + i);
                d = __builtin_nontemporal_load(edst + i);
            } else {
                s = d = i - E;                 // appended self-loops
            }
            int sb = d >> 9;
            pk[j] = ((d & 511) << 17) | s;
            sbv[j] = (unsigned short)sb;
            atomicAdd(&hist[sb], 1);
        } else {
            sbv[j] = 0xFFFFu;
        }
    }
    __syncthreads();

    if (tid < nsb && hist[tid] > 0)
        gbase[tid] = atomicAdd(&sbcur[tid], hist[tid]);
    hist[tid] = 0;
    __syncthreads();

    for (int j = tid; j < CB_CHUNK; j += 256) {
        unsigned short sb = sbv[j];
        if (sb != 0xFFFFu) {
            int pos = gbase[sb] + atomicAdd(&hist[sb], 1);
            __builtin_nontemporal_store(pk[j], packed1 + pos);
        }
    }
}

__global__ __launch_bounds__(256) void sb_sort2(
    const int* __restrict__ sbbase, const int* __restrict__ packed1,
    int* __restrict__ col, int* __restrict__ row_end, int n)
{
    const int sb = blockIdx.x;
    const int node0 = sb << 9;
    const int lo = sbbase[sb];
    const int hi = sbbase[sb + 1];
    const int tid = threadIdx.x;
    __shared__ int c[512];
    __shared__ int sc[512];
    c[tid] = 0; c[tid + 256] = 0;
    __syncthreads();
    for (int j = lo + tid; j < hi; j += 256)
        atomicAdd(&c[((unsigned)packed1[j]) >> 17], 1);
    __syncthreads();
    sc[tid] = c[tid]; sc[tid + 256] = c[tid + 256];
    __syncthreads();
    for (int off = 1; off < 512; off <<= 1) {
        int i0 = tid, i1 = tid + 256;
        int v0 = (i0 >= off) ? sc[i0 - off] : 0;
        int v1 = (i1 >= off) ? sc[i1 - off] : 0;
        __syncthreads();
        sc[i0] += v0; sc[i1] += v1;
        __syncthreads();
    }
    #pragma unroll
    for (int q = 0; q < 2; ++q) {
        int i = tid + q * 256;
        int node = node0 + i;
        if (node < n) row_end[node] = lo + sc[i];
        c[i] = lo + sc[i] - c[i];
    }
    __syncthreads();
    for (int j = lo + tid; j < hi; j += 256) {
        int p = packed1[j];
        int ld = ((unsigned)p) >> 17;
        int pos = atomicAdd(&c[ld], 1);
        __builtin_nontemporal_store(p & 0x1FFFF, col + pos);
    }
}

// ---- Aggregation v2: 4 bf16 features per lane (uint2 gather), LPN=FOUT/4
// lanes per node. Lane-split scores; group-uniform kmax skips tail loads.
// col reads + outp writes are non-temporal (keep L2 for the h gather table).
template <int FOUT>
__global__ __launch_bounds__(256) void gat_aggregate(
    const int* __restrict__ row_end, const int* __restrict__ col,
    const float* __restrict__ a_s, const float* __restrict__ a_d,
    const __hip_bfloat16* __restrict__ h_, const float* __restrict__ bias,
    float* __restrict__ outp, int n, int do_relu)
{
    constexpr int LPN = FOUT / 4;
    constexpr int NPW = 64 / LPN;
    const unsigned short* h = (const unsigned short*)h_;
    const int gwave = (blockIdx.x * 256 + threadIdx.x) >> 6;
    const int lane = threadIdx.x & 63;
    const int node = gwave * NPW + lane / LPN;
    const int lsub = lane % LPN;
    if (node >= n) return;
    const int end = row_end[node];
    const int start = (node == 0) ? 0 : row_end[node - 1];
    const float adn = a_d[node];
    const int egrp = lane & ~(LPN - 1);
    float acc0 = 0.f, acc1 = 0.f, acc2 = 0.f, acc3 = 0.f, den = 0.f;
    for (int j = start; j < end; j += LPN) {
        int kmax = end - j; if (kmax > LPN) kmax = LPN;
        int k_idx = j + lsub;
        int sown = __builtin_nontemporal_load(col + ((k_idx < end) ? k_idx : (end - 1)));
        float eown = a_s[sown] + adn;
        eown = (eown > 0.f) ? eown : NEG_SLOPE * eown;
        float pown = (lsub < kmax) ? __expf(eown) : 0.f;
        for (int k = 0; k < kmax; ++k) {
            int   sk = __shfl(sown, egrp + k);
            float pk = __shfl(pown, egrp + k);
            den += pk;
            uint2 hv = *(const uint2*)(h + (size_t)sk * FOUT + lsub * 4);
            acc0 = fmaf(pk, __uint_as_float(hv.x << 16), acc0);
            acc1 = fmaf(pk, __uint_as_float(hv.x & 0xFFFF0000u), acc1);
            acc2 = fmaf(pk, __uint_as_float(hv.y << 16), acc2);
            acc3 = fmaf(pk, __uint_as_float(hv.y & 0xFFFF0000u), acc3);
        }
    }
    const float4 b4 = *(const float4*)(bias + lsub * 4);
    float inv = 1.f / den;                     // self-loop guarantees den > 0
    float v0 = acc0 * inv + b4.x;
    float v1 = acc1 * inv + b4.y;
    float v2 = acc2 * inv + b4.z;
    float v3 = acc3 * inv + b4.w;
    if (do_relu) {
        v0 = fmaxf(v0, 0.f); v1 = fmaxf(v1, 0.f);
        v2 = fmaxf(v2, 0.f); v3 = fmaxf(v3, 0.f);
    }
    f32x4 o; o.x = v0; o.y = v1; o.z = v2; o.w = v3;
    __builtin_nontemporal_store(o, (f32x4*)(outp + (size_t)node * FOUT + lsub * 4));
}

extern "C" void kernel_launch(void* const* d_in, const int* in_sizes, int n_in,
                              void* d_out, int out_size, void* d_ws, size_t ws_size,
                              hipStream_t stream)
{
    const float* x   = (const float*)d_in[0];
    const int* eidx  = (const int*)d_in[1];
    const float* W1  = (const float*)d_in[2];
    const float* as1 = (const float*)d_in[3];
    const float* ad1 = (const float*)d_in[4];
    const float* b1  = (const float*)d_in[5];
    const float* W2  = (const float*)d_in[6];
    const float* as2 = (const float*)d_in[7];
    const float* ad2 = (const float*)d_in[8];
    const float* b2  = (const float*)d_in[9];
    const float* W3  = (const float*)d_in[10];
    const float* as3 = (const float*)d_in[11];
    const float* ad3 = (const float*)d_in[12];
    const float* b3  = (const float*)d_in[13];

    const int fhid = in_sizes[3];        // 64
    const int fin  = in_sizes[2] / fhid; // 128
    const int fo3  = in_sizes[11];       // 32
    const int n    = in_sizes[0] / fin;  // 100000
    const int E    = in_sizes[1] / 2;    // 1,600,000
    const int Etot = E + n;
    const int nsb  = (n + 511) >> 9;

    const int* esrc = eidx;
    const int* edst = eidx + E;

    float* out = (float*)d_out;
    float* h1  = out + (size_t)n * fo3;
    float* h2  = h1 + (size_t)n * fhid;

    // ws: sbhist[256] | sbbase[260] | sbcur[256] | row_end[n] | packed1[Etot]
    //     | col[Etot] | h_bf16[n*fhid] | a_s[n] | a_d[n]
    int* sbhist   = (int*)d_ws;
    int* sbbase   = sbhist + 256;
    int* sbcur    = sbbase + 260;
    int* row_end  = sbcur + 256;
    int* packed1  = row_end + n;
    int* col      = packed1 + Etot;
    __hip_bfloat16* h = (__hip_bfloat16*)(col + Etot);
    float* a_s    = (float*)(h + (size_t)n * fhid);
    float* a_d    = a_s + n;

    const int nchunks = (Etot + CB_CHUNK - 1) / CB_CHUNK;

    // ---- CSR build (shared by all layers) ----
    (void)hipMemsetAsync(sbhist, 0, 256 * 4, stream);
    sb_hist<<<1024, 256, 0, stream>>>(edst, E, n, sbhist);
    sb_scan<<<1, 256, 0, stream>>>(sbhist, nsb, Etot, sbbase, sbcur);
    chunk_bin<<<nchunks, 256, 0, stream>>>(esrc, edst, E, n, nsb, sbcur, packed1);
    sb_sort2<<<nsb, 256, 0, stream>>>(sbbase, packed1, col, row_end, n);

    const int NLB = (n + 63) / 64;

    // ---- Layer 1: x[128] -> h1[64], relu ----
    node_linear<128, 64><<<NLB, 256, 0, stream>>>(x, W1, as1, ad1, h, a_s, a_d, n);
    gat_aggregate<64><<<(n + 15) / 16, 256, 0, stream>>>(row_end, col, a_s, a_d, h, b1, h1, n, 1);

    // ---- Layer 2: h1[64] -> h2[64], relu ----
    node_linear<64, 64><<<NLB, 256, 0, stream>>>(h1, W2, as2, ad2, h, a_s, a_d, n);
    gat_aggregate<64><<<(n + 15) / 16, 256, 0, stream>>>(row_end, col, a_s, a_d, h, b2, h2, n, 1);

    // ---- Layer 3: h2[64] -> out[32], no relu ----
    node_linear<64, 32><<<NLB, 256, 0, stream>>>(h2, W3, as3, ad3, h, a_s, a_d, n);
    gat_aggregate<32><<<(n + 31) / 32, 256, 0, stream>>>(row_end, col, a_s, a_d, h, b3, out, n, 0);
}

// Round 23
// 292.001 us; speedup vs baseline: 1.3699x; 1.3699x over previous
//
#include <hip/hip_runtime.h>
#include <hip/hip_bf16.h>

#define NEG_SLOPE 0.2f

typedef __attribute__((ext_vector_type(8))) short bf16x8;
typedef __attribute__((ext_vector_type(4))) float f32x4;

__device__ __forceinline__ unsigned short bf16bits(float f) {
    __hip_bfloat16 t = __float2bfloat16(f);
    return *reinterpret_cast<unsigned short*>(&t);
}

// MFMA node transform: 256 threads = 4 waves; block computes 64 nodes x FOUT.
template <int FIN, int FOUT>
__global__ __launch_bounds__(256) void node_linear(
    const float* __restrict__ x, const float* __restrict__ W,
    const float* __restrict__ att_s, const float* __restrict__ att_d,
    __hip_bfloat16* __restrict__ h, float* __restrict__ a_s, float* __restrict__ a_d, int n)
{
    constexpr int RS = FIN + 8;               // padded stride (bf16 units)
    __shared__ unsigned short xt[64 * RS];
    __shared__ unsigned short Wt[FOUT * RS];
    const int tid = threadIdx.x;
    const int base = blockIdx.x * 64;

    for (int i = tid; i < 64 * FIN / 2; i += 256) {
        int node = i / (FIN / 2);
        int k2 = i % (FIN / 2);
        float2 v = make_float2(0.f, 0.f);
        if (base + node < n) v = *(const float2*)(x + (size_t)(base + node) * FIN + k2 * 2);
        unsigned pk = (unsigned)bf16bits(v.x) | ((unsigned)bf16bits(v.y) << 16);
        *(unsigned*)(&xt[node * RS + k2 * 2]) = pk;
    }
    for (int i = tid; i < FIN * FOUT; i += 256) {
        int k = i / FOUT, f = i % FOUT;
        Wt[f * RS + k] = bf16bits(W[i]);
    }
    __syncthreads();

    const int wv = tid >> 6, lane = tid & 63;
    const int m = lane & 15, b = lane >> 4;
    const int node0 = base + wv * 16;

    float ps[4] = {0,0,0,0}, pd[4] = {0,0,0,0};
    #pragma unroll
    for (int t = 0; t < FOUT / 16; ++t) {
        f32x4 acc = {0.f, 0.f, 0.f, 0.f};
        #pragma unroll
        for (int ks = 0; ks < FIN / 32; ++ks) {
            bf16x8 a  = *(const bf16x8*)(&xt[(wv * 16 + m) * RS + ks * 32 + b * 8]);
            bf16x8 bb = *(const bf16x8*)(&Wt[(t * 16 + m) * RS + ks * 32 + b * 8]);
            acc = __builtin_amdgcn_mfma_f32_16x16x32_bf16(a, bb, acc, 0, 0, 0);
        }
        const float as_c = att_s[t * 16 + m];
        const float ad_c = att_d[t * 16 + m];
        #pragma unroll
        for (int r = 0; r < 4; ++r) {
            float v = acc[r];
            int node = node0 + b * 4 + r;
            if (node < n) h[(size_t)node * FOUT + t * 16 + m] = __float2bfloat16(v);
            ps[r] = fmaf(v, as_c, ps[r]);
            pd[r] = fmaf(v, ad_c, pd[r]);
        }
    }
    #pragma unroll
    for (int r = 0; r < 4; ++r) {
        float s = ps[r], d = pd[r];
        #pragma unroll
        for (int o = 8; o > 0; o >>= 1) { s += __shfl_xor(s, o); d += __shfl_xor(d, o); }
        int node = node0 + b * 4 + r;
        if (m == 0 && node < n) { a_s[node] = s; a_d[node] = d; }
    }
}

// ---- CSR build: SB hist -> tiny scan -> per-chunk SB bin -> per-SB sort ----

__global__ __launch_bounds__(256) void sb_hist(
    const int* __restrict__ edst, int E, int n, int* __restrict__ sbhist)
{
    __shared__ int lh[256];
    const int tid = threadIdx.x;
    lh[tid] = 0;
    __syncthreads();
    const int Etot = E + n;
    const int stride = gridDim.x * 256;
    for (int i = blockIdx.x * 256 + tid; i < Etot; i += stride) {
        int d = (i < E) ? edst[i] : i - E;
        atomicAdd(&lh[d >> 9], 1);
    }
    __syncthreads();
    if (lh[tid] > 0) atomicAdd(&sbhist[tid], lh[tid]);
}

__global__ __launch_bounds__(256) void sb_scan(
    const int* __restrict__ sbhist, int nsb, int Etot,
    int* __restrict__ sbbase, int* __restrict__ sbcur)
{
    __shared__ int buf[256];
    const int tid = threadIdx.x;
    int v = (tid < nsb) ? sbhist[tid] : 0;
    buf[tid] = v;
    __syncthreads();
    for (int off = 1; off < 256; off <<= 1) {
        int t = (tid >= off) ? buf[tid - off] : 0;
        __syncthreads();
        buf[tid] += t;
        __syncthreads();
    }
    if (tid < nsb) {
        int ex = buf[tid] - v;
        sbbase[tid] = ex;
        sbcur[tid] = ex;
    }
    if (tid == 0) sbbase[nsb] = Etot;
}

#define CB_CHUNK 4096
#define CB_NSB_MAX 256
__global__ __launch_bounds__(256) void chunk_bin(
    const int* __restrict__ esrc, const int* __restrict__ edst, int E, int n,
    int nsb, int* __restrict__ sbcur, int* __restrict__ packed1)
{
    __shared__ int pk[CB_CHUNK];
    __shared__ unsigned short sbv[CB_CHUNK];
    __shared__ int hist[CB_NSB_MAX];
    __shared__ int gbase[CB_NSB_MAX];
    const int tid = threadIdx.x;
    const int i0 = blockIdx.x * CB_CHUNK;
    const int Etot = E + n;

    hist[tid] = 0;
    __syncthreads();

    for (int j = tid; j < CB_CHUNK; j += 256) {
        int i = i0 + j;
        if (i < Etot) {
            int s, d;
            if (i < E) { s = esrc[i]; d = edst[i]; }
            else       { s = d = i - E; }
            int sb = d >> 9;
            pk[j] = ((d & 511) << 17) | s;
            sbv[j] = (unsigned short)sb;
            atomicAdd(&hist[sb], 1);
        } else {
            sbv[j] = 0xFFFFu;
        }
    }
    __syncthreads();

    if (tid < nsb && hist[tid] > 0)
        gbase[tid] = atomicAdd(&sbcur[tid], hist[tid]);
    hist[tid] = 0;
    __syncthreads();

    for (int j = tid; j < CB_CHUNK; j += 256) {
        unsigned short sb = sbv[j];
        if (sb != 0xFFFFu) {
            int pos = gbase[sb] + atomicAdd(&hist[sb], 1);
            packed1[pos] = pk[j];
        }
    }
}

__global__ __launch_bounds__(256) void sb_sort2(
    const int* __restrict__ sbbase, const int* __restrict__ packed1,
    int* __restrict__ col, int* __restrict__ row_end, int n)
{
    const int sb = blockIdx.x;
    const int node0 = sb << 9;
    const int lo = sbbase[sb];
    const int hi = sbbase[sb + 1];
    const int tid = threadIdx.x;
    __shared__ int c[512];
    __shared__ int sc[512];
    c[tid] = 0; c[tid + 256] = 0;
    __syncthreads();
    for (int j = lo + tid; j < hi; j += 256)
        atomicAdd(&c[((unsigned)packed1[j]) >> 17], 1);
    __syncthreads();
    sc[tid] = c[tid]; sc[tid + 256] = c[tid + 256];
    __syncthreads();
    for (int off = 1; off < 512; off <<= 1) {
        int i0 = tid, i1 = tid + 256;
        int v0 = (i0 >= off) ? sc[i0 - off] : 0;
        int v1 = (i1 >= off) ? sc[i1 - off] : 0;
        __syncthreads();
        sc[i0] += v0; sc[i1] += v1;
        __syncthreads();
    }
    #pragma unroll
    for (int q = 0; q < 2; ++q) {
        int i = tid + q * 256;
        int node = node0 + i;
        if (node < n) row_end[node] = lo + sc[i];
        c[i] = lo + sc[i] - c[i];
    }
    __syncthreads();
    for (int j = lo + tid; j < hi; j += 256) {
        int p = packed1[j];
        int ld = ((unsigned)p) >> 17;
        int pos = atomicAdd(&c[ld], 1);
        col[pos] = p & 0x1FFFF;
    }
}

// ---- Aggregation v2: 4 bf16 features per lane (uint2 gather), LPN=FOUT/4
// lanes per node. Lane-split scores; group-uniform kmax skips tail loads.
template <int FOUT>
__global__ __launch_bounds__(256) void gat_aggregate(
    const int* __restrict__ row_end, const int* __restrict__ col,
    const float* __restrict__ a_s, const float* __restrict__ a_d,
    const __hip_bfloat16* __restrict__ h_, const float* __restrict__ bias,
    float* __restrict__ outp, int n, int do_relu)
{
    constexpr int LPN = FOUT / 4;
    constexpr int NPW = 64 / LPN;
    const unsigned short* h = (const unsigned short*)h_;
    const int gwave = (blockIdx.x * 256 + threadIdx.x) >> 6;
    const int lane = threadIdx.x & 63;
    const int node = gwave * NPW + lane / LPN;
    const int lsub = lane % LPN;
    if (node >= n) return;
    const int end = row_end[node];
    const int start = (node == 0) ? 0 : row_end[node - 1];
    const float adn = a_d[node];
    const int egrp = lane & ~(LPN - 1);
    float acc0 = 0.f, acc1 = 0.f, acc2 = 0.f, acc3 = 0.f, den = 0.f;
    for (int j = start; j < end; j += LPN) {
        int kmax = end - j; if (kmax > LPN) kmax = LPN;
        int k_idx = j + lsub;
        int sown = col[(k_idx < end) ? k_idx : (end - 1)];
        float eown = a_s[sown] + adn;
        eown = (eown > 0.f) ? eown : NEG_SLOPE * eown;
        float pown = (lsub < kmax) ? __expf(eown) : 0.f;
        for (int k = 0; k < kmax; ++k) {
            int   sk = __shfl(sown, egrp + k);
            float pk = __shfl(pown, egrp + k);
            den += pk;
            uint2 hv = *(const uint2*)(h + (size_t)sk * FOUT + lsub * 4);
            acc0 = fmaf(pk, __uint_as_float(hv.x << 16), acc0);
            acc1 = fmaf(pk, __uint_as_float(hv.x & 0xFFFF0000u), acc1);
            acc2 = fmaf(pk, __uint_as_float(hv.y << 16), acc2);
            acc3 = fmaf(pk, __uint_as_float(hv.y & 0xFFFF0000u), acc3);
        }
    }
    const float4 b4 = *(const float4*)(bias + lsub * 4);
    float inv = 1.f / den;                     // self-loop guarantees den > 0
    float v0 = acc0 * inv + b4.x;
    float v1 = acc1 * inv + b4.y;
    float v2 = acc2 * inv + b4.z;
    float v3 = acc3 * inv + b4.w;
    if (do_relu) {
        v0 = fmaxf(v0, 0.f); v1 = fmaxf(v1, 0.f);
        v2 = fmaxf(v2, 0.f); v3 = fmaxf(v3, 0.f);
    }
    float4 o; o.x = v0; o.y = v1; o.z = v2; o.w = v3;
    *(float4*)(outp + (size_t)node * FOUT + lsub * 4) = o;
}

extern "C" void kernel_launch(void* const* d_in, const int* in_sizes, int n_in,
                              void* d_out, int out_size, void* d_ws, size_t ws_size,
                              hipStream_t stream)
{
    const float* x   = (const float*)d_in[0];
    const int* eidx  = (const int*)d_in[1];
    const float* W1  = (const float*)d_in[2];
    const float* as1 = (const float*)d_in[3];
    const float* ad1 = (const float*)d_in[4];
    const float* b1  = (const float*)d_in[5];
    const float* W2  = (const float*)d_in[6];
    const float* as2 = (const float*)d_in[7];
    const float* ad2 = (const float*)d_in[8];
    const float* b2  = (const float*)d_in[9];
    const float* W3  = (const float*)d_in[10];
    const float* as3 = (const float*)d_in[11];
    const float* ad3 = (const float*)d_in[12];
    const float* b3  = (const float*)d_in[13];

    const int fhid = in_sizes[3];        // 64
    const int fin  = in_sizes[2] / fhid; // 128
    const int fo3  = in_sizes[11];       // 32
    const int n    = in_sizes[0] / fin;  // 100000
    const int E    = in_sizes[1] / 2;    // 1,600,000
    const int Etot = E + n;
    const int nsb  = (n + 511) >> 9;

    const int* esrc = eidx;
    const int* edst = eidx + E;

    float* out = (float*)d_out;
    float* h1  = out + (size_t)n * fo3;
    float* h2  = h1 + (size_t)n * fhid;

    // ws: sbhist[256] | sbbase[260] | sbcur[256] | row_end[n] | packed1[Etot]
    //     | col[Etot] | h_bf16[n*fhid] | a_s[n] | a_d[n]
    int* sbhist   = (int*)d_ws;
    int* sbbase   = sbhist + 256;
    int* sbcur    = sbbase + 260;
    int* row_end  = sbcur + 256;
    int* packed1  = row_end + n;
    int* col      = packed1 + Etot;
    __hip_bfloat16* h = (__hip_bfloat16*)(col + Etot);
    float* a_s    = (float*)(h + (size_t)n * fhid);
    float* a_d    = a_s + n;

    const int nchunks = (Etot + CB_CHUNK - 1) / CB_CHUNK;

    // ---- CSR build (shared by all layers) ----
    (void)hipMemsetAsync(sbhist, 0, 256 * 4, stream);
    sb_hist<<<1024, 256, 0, stream>>>(edst, E, n, sbhist);
    sb_scan<<<1, 256, 0, stream>>>(sbhist, nsb, Etot, sbbase, sbcur);
    chunk_bin<<<nchunks, 256, 0, stream>>>(esrc, edst, E, n, nsb, sbcur, packed1);
    sb_sort2<<<nsb, 256, 0, stream>>>(sbbase, packed1, col, row_end, n);

    const int NLB = (n + 63) / 64;

    // ---- Layer 1: x[128] -> h1[64], relu ----
    node_linear<128, 64><<<NLB, 256, 0, stream>>>(x, W1, as1, ad1, h, a_s, a_d, n);
    gat_aggregate<64><<<(n + 15) / 16, 256, 0, stream>>>(row_end, col, a_s, a_d, h, b1, h1, n, 1);

    // ---- Layer 2: h1[64] -> h2[64], relu ----
    node_linear<64, 64><<<NLB, 256, 0, stream>>>(h1, W2, as2, ad2, h, a_s, a_d, n);
    gat_aggregate<64><<<(n + 15) / 16, 256, 0, stream>>>(row_end, col, a_s, a_d, h, b2, h2, n, 1);

    // ---- Layer 3: h2[64] -> out[32], no relu ----
    node_linear<64, 32><<<NLB, 256, 0, stream>>>(h2, W3, as3, ad3, h, a_s, a_d, n);
    gat_aggregate<32><<<(n + 31) / 32, 256, 0, stream>>>(row_end, col, a_s, a_d, h, b3, out, n, 0);
}